// Round 22
// baseline (8969.257 us; speedup 1.0000x reference)
//
#include <hip/hip_runtime.h>
#include <math.h>

#define D 256
#define SEQ 1000
#define NB 32
#define PATCH 160
#define NL 6
#define M_TOTAL (NB * SEQ)   // 32000
#define G3 (3 * D)           // 768

typedef _Float16 half8 __attribute__((ext_vector_type(8)));
typedef float f32x4 __attribute__((ext_vector_type(4)));

__device__ __forceinline__ float gelu_exact(float v) {
    return 0.5f * v * (1.0f + erff(v * 0.70710678118654752440f));
}

// Raw workgroup barrier: orders LDS (lgkmcnt) but does NOT drain vmcnt.
// (Harness-verified in rounds 3, 6, 7, 9, 12, 13, 16, 21.)
__device__ __forceinline__ void bar_lds() {
    asm volatile("s_waitcnt lgkmcnt(0)" ::: "memory");
    __builtin_amdgcn_s_barrier();
    asm volatile("" ::: "memory");
}

// Fast sigmoid/tanh on native HW transcendentals (r21-proven, passed).
__device__ __forceinline__ float fast_sigmoid(float g) {
    float e = __builtin_amdgcn_exp2f(-1.44269504f * g);
    return __builtin_amdgcn_rcpf(1.f + e);
}
__device__ __forceinline__ float fast_tanh(float a) {
    a = fminf(fmaxf(a, -12.f), 12.f);
    float t = __builtin_amdgcn_exp2f(2.88539008f * a);
    return (t - 1.f) * __builtin_amdgcn_rcpf(t + 1.f);
}

// Packed dot2 (r13-proven): acc += w.lo16*h.lo16 + w.hi16*h.hi16.
#define DOT(acc, w, h) asm("v_dot2_f32_f16 %0, %1, %2, %0" \
                           : "+v"(acc) : "v"(w), "v"(h))

// ---------------------------------------------------------------------------
// Kernel 1: conv patchify GEMM + exact GELU + pos_emb add
// ---------------------------------------------------------------------------
__global__ __launch_bounds__(256) void conv_gelu_pos(
    const float* __restrict__ wav, const float* __restrict__ cw,
    const float* __restrict__ pos, float* __restrict__ x)
{
    __shared__ float As[64][33];
    __shared__ float Bs[32][65];
    const int m0 = blockIdx.x * 64;
    const int n0 = blockIdx.y * 64;
    const int tid = threadIdx.x;
    const int tx = tid & 15;      // 0..15 -> n
    const int ty = tid >> 4;      // 0..15 -> m
    float acc[4][4] = {};

    for (int kc = 0; kc < PATCH; kc += 32) {
        for (int p = 0; p < 8; ++p) {
            int mr = p * 8 + (tid >> 5);
            int kk = tid & 31;
            int m = m0 + mr;
            int b = m / SEQ, s = m % SEQ;
            As[mr][kk] = wav[(size_t)b * 160000 + (size_t)s * PATCH + kc + kk];
        }
        for (int p = 0; p < 8; ++p) {
            int kr = p * 4 + (tid >> 6);
            int nn = tid & 63;
            Bs[kr][nn] = cw[(size_t)(kc + kr) * D + n0 + nn];
        }
        __syncthreads();
        #pragma unroll
        for (int kk = 0; kk < 32; ++kk) {
            float a[4], bb[4];
            #pragma unroll
            for (int i = 0; i < 4; ++i) a[i] = As[ty * 4 + i][kk];
            #pragma unroll
            for (int j = 0; j < 4; ++j) bb[j] = Bs[kk][tx * 4 + j];
            #pragma unroll
            for (int i = 0; i < 4; ++i)
                #pragma unroll
                for (int j = 0; j < 4; ++j)
                    acc[i][j] = fmaf(a[i], bb[j], acc[i][j]);
        }
        __syncthreads();
    }
    #pragma unroll
    for (int i = 0; i < 4; ++i) {
        int m = m0 + ty * 4 + i;
        int s = m % SEQ;
        int n = n0 + tx * 4;
        float4 v;
        v.x = gelu_exact(acc[i][0]) + pos[(size_t)s * D + n + 0];
        v.y = gelu_exact(acc[i][1]) + pos[(size_t)s * D + n + 1];
        v.z = gelu_exact(acc[i][2]) + pos[(size_t)s * D + n + 2];
        v.w = gelu_exact(acc[i][3]) + pos[(size_t)s * D + n + 3];
        *(float4*)&x[(size_t)m * D + n] = v;
    }
}

// ---------------------------------------------------------------------------
// Kernel 2: per-row mean / rstd (LayerNorm stats). One wave per row.
// ---------------------------------------------------------------------------
__global__ __launch_bounds__(64) void row_stats(
    const float* __restrict__ x, float* __restrict__ st)
{
    const int m = blockIdx.x;
    const int t = threadIdx.x;
    const float* r = x + (size_t)m * D;
    float s = 0.f, q = 0.f;
    #pragma unroll
    for (int i = 0; i < 4; ++i) {
        float v = r[t + 64 * i];
        s += v;
        q += v * v;
    }
    #pragma unroll
    for (int o = 32; o > 0; o >>= 1) {
        s += __shfl_down(s, o);
        q += __shfl_down(q, o);
    }
    if (t == 0) {
        float mu = s * (1.f / 256.f);
        float var = q * (1.f / 256.f) - mu * mu;
        st[2 * m]     = mu;
        st[2 * m + 1] = rsqrtf(var + 1e-5f);
    }
}

// ---------------------------------------------------------------------------
// Kernel 3: fused LN + input-projection GEMM
// ---------------------------------------------------------------------------
__global__ __launch_bounds__(256) void ln_xp_gemm(
    const float* __restrict__ x, const float* __restrict__ st,
    const float* __restrict__ lnsc, const float* __restrict__ lnbi,
    const float* __restrict__ wih, const float* __restrict__ bih,
    float* __restrict__ xp)
{
    __shared__ float As[64][33];
    __shared__ float Bs[32][65];
    __shared__ float sc[D], bi[D];
    const int m0 = blockIdx.x * 64;
    const int n0 = blockIdx.y * 64;
    const int tid = threadIdx.x;
    const int tx = tid & 15;
    const int ty = tid >> 4;
    sc[tid] = lnsc[tid];
    bi[tid] = lnbi[tid];
    float acc[4][4] = {};

    for (int kc = 0; kc < D; kc += 32) {
        for (int p = 0; p < 8; ++p) {
            int mr = p * 8 + (tid >> 5);
            int kk = tid & 31;
            int m = m0 + mr;
            float mu = st[2 * m], rs = st[2 * m + 1];
            float v = x[(size_t)m * D + kc + kk];
            As[mr][kk] = (v - mu) * rs * sc[kc + kk] + bi[kc + kk];
        }
        for (int p = 0; p < 8; ++p) {
            int nr = p * 8 + (tid >> 5);
            int kk = tid & 31;
            Bs[kk][nr] = wih[(size_t)(n0 + nr) * D + kc + kk];
        }
        __syncthreads();
        #pragma unroll
        for (int kk = 0; kk < 32; ++kk) {
            float a[4], bb[4];
            #pragma unroll
            for (int i = 0; i < 4; ++i) a[i] = As[ty * 4 + i][kk];
            #pragma unroll
            for (int j = 0; j < 4; ++j) bb[j] = Bs[kk][tx * 4 + j];
            #pragma unroll
            for (int i = 0; i < 4; ++i)
                #pragma unroll
                for (int j = 0; j < 4; ++j)
                    acc[i][j] = fmaf(a[i], bb[j], acc[i][j]);
        }
        __syncthreads();
    }
    #pragma unroll
    for (int i = 0; i < 4; ++i) {
        int m = m0 + ty * 4 + i;
        int n = n0 + tx * 4;
        float4 v;
        v.x = acc[i][0] + bih[n + 0];
        v.y = acc[i][1] + bih[n + 1];
        v.z = acc[i][2] + bih[n + 2];
        v.w = acc[i][3] + bih[n + 3];
        *(float4*)&xp[(size_t)m * G3 + n] = v;
    }
}

// ---------------------------------------------------------------------------
// Kernel 4: pack w_hh fp32 -> (a) fp16 MFMA B-fragments for gates r,z
// (rows 0..511), (b) k-pair-packed dot2 words for gate n (rows 512..767).
// (a) idx<65536: tile t (0..31), chunk c, lane l, word j:
//     n = 16t + (l&15), k = 32c + 8*(l>>4) + 2j  -> wfrag[idx]
// (b) else: m = idx-65536: d = m&255, s = m>>8 (0..127 pair index, k=2s)
//     wn16[s*256 + d] = pack(W[2D+d][2s], W[2D+d][2s+1])
// ---------------------------------------------------------------------------
__global__ __launch_bounds__(256) void pack_whh(
    const float* __restrict__ whh, unsigned int* __restrict__ wfrag,
    unsigned int* __restrict__ wn16)
{
    const int idx = blockIdx.x * 256 + threadIdx.x;   // 0..98303
    if (idx < 65536) {
        const int j = idx & 3;
        const int l = (idx >> 2) & 63;
        const int c = (idx >> 8) & 7;
        const int t = idx >> 11;                      // 0..31
        const int n = t * 16 + (l & 15);              // r,z rows
        const int k = c * 32 + (l >> 4) * 8 + 2 * j;
        unsigned short lo = __builtin_bit_cast(unsigned short, (_Float16)whh[(size_t)n * D + k]);
        unsigned short hi = __builtin_bit_cast(unsigned short, (_Float16)whh[(size_t)n * D + k + 1]);
        wfrag[idx] = (unsigned int)lo | ((unsigned int)hi << 16);
    } else {
        const int m = idx - 65536;                    // 0..32767
        const int d = m & 255;
        const int s = m >> 8;                         // 0..127
        const size_t row = (size_t)(2 * D + d) * D + 2 * s;
        unsigned short lo = __builtin_bit_cast(unsigned short, (_Float16)whh[row]);
        unsigned short hi = __builtin_bit_cast(unsigned short, (_Float16)whh[row + 1]);
        wn16[(size_t)s * 256 + d] = (unsigned int)lo | ((unsigned int)hi << 16);
    }
}

// ---------------------------------------------------------------------------
// Kernel 5: GRU recurrence — hybrid MFMA(r,z) ∥ VALU-dot2(n).
//
// r21 post-mortem: step 2640cy = MFMA 1546 (384 MFMA/block, pipe-bound) +
// gates ~300 + overhead ~800; VALU idle during the MFMA phase (2.2% busy).
// This round: r,z stay on the matrix pipe (256 MFMA -> ~1030cy/SIMD); the
// n-gate moves to the VALU via r13's proven v_dot2_f32_f16 (64 packed
// containers/thread, K-half split over kh=tid>>8) and runs CONCURRENTLY
// (m114: MFMA+VALU pipes co-schedule; dot2 ~256-512cy hidden under 1030).
// AGPR pressure drops (128 vs 192 frag words); 64 dot2 containers + ~50
// working ~= 114 arch regs (r13's spill threshold was 192).
// Gates: an = own kh0 partial + prn[d] (kh1 partial, LDS) + bias.
// Everything else (fast gates, hreg, h16 pack, 2 bar_lds) = r21 verbatim.
// ---------------------------------------------------------------------------
__global__ __launch_bounds__(512, 1) void gru_scan_mfma(
    const float* __restrict__ xp, const unsigned int* __restrict__ wfrag,
    const unsigned int* __restrict__ wn16,
    const float* __restrict__ bhh, float* __restrict__ x)
{
    __shared__ __align__(16) unsigned int h16_lds[D / 2];  // packed fp16 pairs
    __shared__ float gate_lds[512];     // r: [0..255], z: [256..511]
    __shared__ float prn[D];            // kh=1 n-gate partials
    const int tid  = threadIdx.x;
    const int w    = tid >> 6;          // wave 0..7
    const int l    = tid & 63;          // lane
    const int d    = tid & 255;         // output dim (gates; dot2 row)
    const int kh   = tid >> 8;          // K-half for the n-gate dot2
    const int batch = blockIdx.x;

    // --- r,z weights: 32 B-fragments = 128 u32/thread (AGPR-parked) --------
    half8 bf[4][8];
    {
        #pragma unroll
        for (int i = 0; i < 4; ++i)
            #pragma unroll
            for (int c = 0; c < 8; ++c) {
                const uint4 v = *(const uint4*)(
                    wfrag + ((size_t)(((w * 4 + i) * 8 + c) * 64 + l)) * 4);
                bf[i][c] = __builtin_bit_cast(half8, v);
            }
    }
    // --- n-gate weights: 64 packed pairs in float containers (arch VGPRs) --
    float wnA[32], wnB[32];
    {
        const unsigned int* wb = wn16 + (size_t)kh * 64 * 256 + d;
        #pragma unroll
        for (int j = 0; j < 32; ++j) wnA[j] = __uint_as_float(wb[(size_t)j * 256]);
        #pragma unroll
        for (int j = 0; j < 32; ++j) wnB[j] = __uint_as_float(wb[(size_t)(32 + j) * 256]);
    }
    float bh_r = 0.f, bh_z = 0.f, bh_n = 0.f;
    if (tid < D) {
        bh_r = bhh[d];
        bh_z = bhh[D + d];
        bh_n = bhh[2 * D + d];
    }

    const float* xpb = xp + (size_t)batch * SEQ * G3;
    float* xb = x + (size_t)batch * SEQ * D;

    float hreg = 0.f;                   // fp32 h state, register-resident
    if (tid < D / 2) h16_lds[tid] = 0u;
    __syncthreads();

    const int lg = l >> 4;              // lane group 0..3
    const unsigned int* hp_base = h16_lds + kh * 64;  // this K-half's pairs
    for (int t = 0; t < SEQ; ++t) {
        // xp + residual loads early (tid<256); latency hides under MFMA
        float xr = 0.f, xz = 0.f, xn_ = 0.f, xold = 0.f;
        if (tid < D) {
            const float* xpt = xpb + (size_t)t * G3;
            xr   = xpt[d];
            xz   = xpt[D + d];
            xn_  = xpt[2 * D + d];
            xold = xb[(size_t)t * D + d];
        }

        // --- A fragments: h replicated across rows; broadcast LDS reads ----
        half8 af[8];
        #pragma unroll
        for (int c = 0; c < 8; ++c)
            af[c] = __builtin_bit_cast(half8,
                *(const uint4*)(h16_lds + 16 * c + 4 * lg));

        // --- MFMA phase (matrix pipe): r,z = 4 tiles x 8 K-chunks ----------
        #pragma unroll
        for (int i = 0; i < 4; ++i) {
            f32x4 cf = {0.f, 0.f, 0.f, 0.f};
            #pragma unroll
            for (int c = 0; c < 8; ++c)
                cf = __builtin_amdgcn_mfma_f32_16x16x32_f16(af[c], bf[i][c], cf, 0, 0, 0);
            if (l < 16) gate_lds[(w * 4 + i) * 16 + l] = cf[0];  // row 0
        }

        // --- dot2 phase (VALU pipe, overlaps MFMA): n-gate K-half ----------
        float an_p = 0.f;
        #pragma unroll
        for (int c = 0; c < 8; ++c) {          // pairs 4c..4c+3
            uint4 hp = *(const uint4*)(hp_base + 4 * c);
            DOT(an_p, wnA[4*c+0], hp.x); DOT(an_p, wnA[4*c+1], hp.y);
            DOT(an_p, wnA[4*c+2], hp.z); DOT(an_p, wnA[4*c+3], hp.w);
        }
        #pragma unroll
        for (int c = 0; c < 8; ++c) {          // pairs 32+4c..
            uint4 hp = *(const uint4*)(hp_base + 32 + 4 * c);
            DOT(an_p, wnB[4*c+0], hp.x); DOT(an_p, wnB[4*c+1], hp.y);
            DOT(an_p, wnB[4*c+2], hp.z); DOT(an_p, wnB[4*c+3], hp.w);
        }
        if (kh) prn[d] = an_p;
        bar_lds();

        // --- gates (tid<256): native exp2/rcp, h in register ---------------
        if (tid < D) {
            float r = fast_sigmoid(xr + gate_lds[d]       + bh_r);
            float z = fast_sigmoid(xz + gate_lds[256 + d] + bh_z);
            float an = an_p + prn[d] + bh_n;
            float n = fast_tanh(xn_ + r * an);
            float hnew = (1.f - z) * n + z * hreg;
            hreg = hnew;
            // pack (h[d], h[d+1]) -> fp16 pair; neighbors are adjacent lanes
            float hn1 = __shfl_down(hnew, 1);
            if (!(d & 1)) {
                unsigned short l0 = __builtin_bit_cast(unsigned short, (_Float16)hnew);
                unsigned short l1 = __builtin_bit_cast(unsigned short, (_Float16)hn1);
                h16_lds[d >> 1] = (unsigned int)l0 | ((unsigned int)l1 << 16);
            }
            xb[(size_t)t * D + d] = xold + hnew;
        }
        bar_lds();
    }
}

// ---------------------------------------------------------------------------
// Kernel 6: final LN + mean-pool over sequence
// ---------------------------------------------------------------------------
__global__ __launch_bounds__(256) void pool_ln(
    const float* __restrict__ x, const float* __restrict__ st,
    const float* __restrict__ fsc, const float* __restrict__ fbi,
    float* __restrict__ emb)
{
    const int b = blockIdx.x;
    const int d = threadIdx.x;
    float acc = 0.f;
    for (int s = 0; s < SEQ; ++s) {
        int m = b * SEQ + s;
        acc += (x[(size_t)m * D + d] - st[2 * m]) * st[2 * m + 1];
    }
    emb[b * D + d] = (acc * (1.f / (float)SEQ)) * fsc[d] + fbi[d];
}

// ---------------------------------------------------------------------------
// Kernel 7: classification head (tiny). Single block.
// ---------------------------------------------------------------------------
__global__ __launch_bounds__(256) void head_mlp(
    const float* __restrict__ emb, const float* __restrict__ w1,
    const float* __restrict__ b1, const float* __restrict__ w2,
    const float* __restrict__ b2, float* __restrict__ out)
{
    __shared__ float es[NB][D + 1];
    __shared__ float h1[NB][128 + 1];
    const int t = threadIdx.x;
    for (int i = t; i < NB * D; i += 256) es[i / D][i % D] = emb[i];
    __syncthreads();
    for (int i = t; i < NB * 128; i += 256) {
        int bb = i / 128, j = i % 128;
        float a = b1[j];
        for (int k = 0; k < D; ++k) a = fmaf(es[bb][k], w1[(size_t)k * 128 + j], a);
        h1[bb][j] = gelu_exact(a);
    }
    __syncthreads();
    for (int i = t; i < NB * 8; i += 256) {
        int bb = i / 8, c = i % 8;
        float a = b2[c];
        for (int k = 0; k < 128; ++k) a = fmaf(h1[bb][k], w2[(size_t)k * 8 + c], a);
        out[i] = a;
    }
}

// ---------------------------------------------------------------------------
extern "C" void kernel_launch(void* const* d_in, const int* in_sizes, int n_in,
                              void* d_out, int out_size, void* d_ws, size_t ws_size,
                              hipStream_t stream)
{
    const float* wav  = (const float*)d_in[0];
    const float* cw   = (const float*)d_in[1];
    const float* pos  = (const float*)d_in[2];
    const float* lnsc = (const float*)d_in[3];
    const float* lnbi = (const float*)d_in[4];
    const float* wih  = (const float*)d_in[5];
    const float* whh  = (const float*)d_in[6];
    const float* bih  = (const float*)d_in[7];
    const float* bhh  = (const float*)d_in[8];
    const float* fsc  = (const float*)d_in[9];
    const float* fbi  = (const float*)d_in[10];
    const float* hw1  = (const float*)d_in[11];
    const float* hb1  = (const float*)d_in[12];
    const float* hw2  = (const float*)d_in[13];
    const float* hb2  = (const float*)d_in[14];

    float* ws    = (float*)d_ws;
    float* x     = ws;                        // 8,192,000 f
    float* xp    = x + (size_t)M_TOTAL * D;   // 24,576,000 f
    float* st    = xp + (size_t)M_TOTAL * G3; // 64,000 f
    unsigned int* wfrag = (unsigned int*)(st + 2 * M_TOTAL); // 65,536 u32
    unsigned int* wn16  = wfrag + 65536;                     // 32,768 u32
    float* emb   = (float*)(wfrag + 98304);   // 8,192 f

    conv_gelu_pos<<<dim3(M_TOTAL / 64, D / 64), 256, 0, stream>>>(wav, cw, pos, x);

    for (int l = 0; l < NL; ++l) {
        row_stats<<<M_TOTAL, 64, 0, stream>>>(x, st);
        ln_xp_gemm<<<dim3(M_TOTAL / 64, G3 / 64), 256, 0, stream>>>(
            x, st, lnsc + (size_t)l * D, lnbi + (size_t)l * D,
            wih + (size_t)l * G3 * D, bih + (size_t)l * G3, xp);
        pack_whh<<<384, 256, 0, stream>>>(whh + (size_t)l * G3 * D, wfrag, wn16);
        gru_scan_mfma<<<NB, 512, 0, stream>>>(
            xp, wfrag, wn16, bhh + (size_t)l * G3, x);
    }

    row_stats<<<M_TOTAL, 64, 0, stream>>>(x, st);
    pool_ln<<<NB, D, 0, stream>>>(x, st, fsc, fbi, emb);
    head_mlp<<<1, 256, 0, stream>>>(emb, hw1, hb1, hw2, hb2, (float*)d_out);
}

// Round 23
// 7431.335 us; speedup vs baseline: 1.2070x; 1.2070x over previous
//
#include <hip/hip_runtime.h>
#include <math.h>

#define D 256
#define SEQ 1000
#define NB 32
#define PATCH 160
#define NL 6
#define M_TOTAL (NB * SEQ)   // 32000
#define G3 (3 * D)           // 768
#define LDK 132              // padded u32 (k-pair) stride for MFMA staging

typedef _Float16 half8 __attribute__((ext_vector_type(8)));
typedef float f32x4 __attribute__((ext_vector_type(4)));

__device__ __forceinline__ float gelu_exact(float v) {
    return 0.5f * v * (1.0f + erff(v * 0.70710678118654752440f));
}

// Raw workgroup barrier: orders LDS (lgkmcnt) but does NOT drain vmcnt.
// (Harness-verified in rounds 3, 6, 7, 9, 12, 13, 16, 21.)
__device__ __forceinline__ void bar_lds() {
    asm volatile("s_waitcnt lgkmcnt(0)" ::: "memory");
    __builtin_amdgcn_s_barrier();
    asm volatile("" ::: "memory");
}

// Fast sigmoid/tanh on native HW transcendentals (r21-proven, passed).
__device__ __forceinline__ float fast_sigmoid(float g) {
    float e = __builtin_amdgcn_exp2f(-1.44269504f * g);
    return __builtin_amdgcn_rcpf(1.f + e);
}
__device__ __forceinline__ float fast_tanh(float a) {
    a = fminf(fmaxf(a, -12.f), 12.f);
    float t = __builtin_amdgcn_exp2f(2.88539008f * a);
    return (t - 1.f) * __builtin_amdgcn_rcpf(t + 1.f);
}

__device__ __forceinline__ unsigned int pk2(float a, float b) {
    unsigned short lo = __builtin_bit_cast(unsigned short, (_Float16)a);
    unsigned short hi = __builtin_bit_cast(unsigned short, (_Float16)b);
    return (unsigned int)lo | ((unsigned int)hi << 16);
}

// ---------------------------------------------------------------------------
// Kernel 1: conv patchify GEMM + exact GELU + pos_emb add
// ---------------------------------------------------------------------------
__global__ __launch_bounds__(256) void conv_gelu_pos(
    const float* __restrict__ wav, const float* __restrict__ cw,
    const float* __restrict__ pos, float* __restrict__ x)
{
    __shared__ float As[64][33];
    __shared__ float Bs[32][65];
    const int m0 = blockIdx.x * 64;
    const int n0 = blockIdx.y * 64;
    const int tid = threadIdx.x;
    const int tx = tid & 15;      // 0..15 -> n
    const int ty = tid >> 4;      // 0..15 -> m
    float acc[4][4] = {};

    for (int kc = 0; kc < PATCH; kc += 32) {
        for (int p = 0; p < 8; ++p) {
            int mr = p * 8 + (tid >> 5);
            int kk = tid & 31;
            int m = m0 + mr;
            int b = m / SEQ, s = m % SEQ;
            As[mr][kk] = wav[(size_t)b * 160000 + (size_t)s * PATCH + kc + kk];
        }
        for (int p = 0; p < 8; ++p) {
            int kr = p * 4 + (tid >> 6);
            int nn = tid & 63;
            Bs[kr][nn] = cw[(size_t)(kc + kr) * D + n0 + nn];
        }
        __syncthreads();
        #pragma unroll
        for (int kk = 0; kk < 32; ++kk) {
            float a[4], bb[4];
            #pragma unroll
            for (int i = 0; i < 4; ++i) a[i] = As[ty * 4 + i][kk];
            #pragma unroll
            for (int j = 0; j < 4; ++j) bb[j] = Bs[kk][tx * 4 + j];
            #pragma unroll
            for (int i = 0; i < 4; ++i)
                #pragma unroll
                for (int j = 0; j < 4; ++j)
                    acc[i][j] = fmaf(a[i], bb[j], acc[i][j]);
        }
        __syncthreads();
    }
    #pragma unroll
    for (int i = 0; i < 4; ++i) {
        int m = m0 + ty * 4 + i;
        int s = m % SEQ;
        int n = n0 + tx * 4;
        float4 v;
        v.x = gelu_exact(acc[i][0]) + pos[(size_t)s * D + n + 0];
        v.y = gelu_exact(acc[i][1]) + pos[(size_t)s * D + n + 1];
        v.z = gelu_exact(acc[i][2]) + pos[(size_t)s * D + n + 2];
        v.w = gelu_exact(acc[i][3]) + pos[(size_t)s * D + n + 3];
        *(float4*)&x[(size_t)m * D + n] = v;
    }
}

// ---------------------------------------------------------------------------
// Kernel 2: per-row mean / rstd (LayerNorm stats). One wave per row.
// ---------------------------------------------------------------------------
__global__ __launch_bounds__(64) void row_stats(
    const float* __restrict__ x, float* __restrict__ st)
{
    const int m = blockIdx.x;
    const int t = threadIdx.x;
    const float* r = x + (size_t)m * D;
    float s = 0.f, q = 0.f;
    #pragma unroll
    for (int i = 0; i < 4; ++i) {
        float v = r[t + 64 * i];
        s += v;
        q += v * v;
    }
    #pragma unroll
    for (int o = 32; o > 0; o >>= 1) {
        s += __shfl_down(s, o);
        q += __shfl_down(q, o);
    }
    if (t == 0) {
        float mu = s * (1.f / 256.f);
        float var = q * (1.f / 256.f) - mu * mu;
        st[2 * m]     = mu;
        st[2 * m + 1] = rsqrtf(var + 1e-5f);
    }
}

// ---------------------------------------------------------------------------
// Kernel 3: fused LN + input-projection GEMM on the MATRIX pipe.
// C[m][n] = LN(x[m])·wih[n] + bih[n], M=32000, N=768, K=256, fp16 operands,
// fp32 accumulate. Block = 64x64 tile, 256 thr (4 waves); wave w computes
// rows w*16..+15 x all 64 cols (4 N-tiles x 8 K-chunks = 32 MFMA).
// Fragment maps (HW-validated this session): A row=l&15, B col=l&15,
// k=(l>>4)*8+j; C col=l&15, row=(l>>4)*4+reg. LDS stride LDK=132 u32
// -> 2-way bank aliasing (free, m136).
// ---------------------------------------------------------------------------
__global__ __launch_bounds__(256) void ln_xp_mfma(
    const float* __restrict__ x, const float* __restrict__ st,
    const float* __restrict__ lnsc, const float* __restrict__ lnbi,
    const float* __restrict__ wih, const float* __restrict__ bih,
    float* __restrict__ xp)
{
    __shared__ unsigned int A16[64 * LDK];
    __shared__ unsigned int B16[64 * LDK];
    __shared__ float sc_s[D], bi_s[D];
    const int m0 = blockIdx.x * 64;
    const int n0 = blockIdx.y * 64;
    const int tid = threadIdx.x;
    const int w = tid >> 6, l = tid & 63;

    sc_s[tid] = lnsc[tid];
    bi_s[tid] = lnbi[tid];
    __syncthreads();

    // --- stage A (LN(x) -> fp16) and B (wih -> fp16): 4 thr/row, 64 k each -
    {
        const int r  = tid >> 2;          // 0..63
        const int p0 = (tid & 3) * 32;    // k-pair offset (32 pairs = 64 k)
        const int m  = m0 + r;
        const float mu = st[2 * m], rs = st[2 * m + 1];
        const float* xr = x + (size_t)m * D + 2 * p0;
        const float* wr = wih + (size_t)(n0 + r) * D + 2 * p0;
        #pragma unroll
        for (int p = 0; p < 32; p += 2) {
            const int k = 2 * (p0 + p);
            float4 v = *(const float4*)(xr + 2 * p);
            A16[r * LDK + p0 + p]     = pk2((v.x - mu) * rs * sc_s[k]     + bi_s[k],
                                            (v.y - mu) * rs * sc_s[k + 1] + bi_s[k + 1]);
            A16[r * LDK + p0 + p + 1] = pk2((v.z - mu) * rs * sc_s[k + 2] + bi_s[k + 2],
                                            (v.w - mu) * rs * sc_s[k + 3] + bi_s[k + 3]);
            float4 u = *(const float4*)(wr + 2 * p);
            B16[r * LDK + p0 + p]     = pk2(u.x, u.y);
            B16[r * LDK + p0 + p + 1] = pk2(u.z, u.w);
        }
    }
    __syncthreads();

    // --- compute: wave w -> rows w*16..+15 ---------------------------------
    const int lr = l & 15, lg = l >> 4;
    uint4 afu[8];
    #pragma unroll
    for (int c = 0; c < 8; ++c)
        afu[c] = *(const uint4*)(A16 + (w * 16 + lr) * LDK + c * 16 + lg * 4);

    #pragma unroll
    for (int tile = 0; tile < 4; ++tile) {
        f32x4 acc = {0.f, 0.f, 0.f, 0.f};
        #pragma unroll
        for (int c = 0; c < 8; ++c) {
            uint4 bfu = *(const uint4*)(B16 + (tile * 16 + lr) * LDK + c * 16 + lg * 4);
            acc = __builtin_amdgcn_mfma_f32_16x16x32_f16(
                __builtin_bit_cast(half8, afu[c]),
                __builtin_bit_cast(half8, bfu), acc, 0, 0, 0);
        }
        const int col  = n0 + tile * 16 + lr;
        const int rowb = m0 + w * 16 + lg * 4;
        const float bb = bih[col];
        #pragma unroll
        for (int reg = 0; reg < 4; ++reg)
            xp[(size_t)(rowb + reg) * G3 + col] = acc[reg] + bb;
    }
}

// ---------------------------------------------------------------------------
// Kernel 4: pack w_hh fp32 -> fp16 MFMA B-fragments (r21 version).
// Tile t (n0=16t, n = gate*256+d over 768), chunk c (k0=32c), lane l, word j:
//   element k = 32c + 8*(l>>4) + 2j,2j+1 ; col n = 16t + (l&15)
// ---------------------------------------------------------------------------
__global__ __launch_bounds__(256) void pack_whh(
    const float* __restrict__ whh, unsigned int* __restrict__ wfrag)
{
    const int idx = blockIdx.x * 256 + threadIdx.x;   // 0..98303
    const int j = idx & 3;
    const int l = (idx >> 2) & 63;
    const int c = (idx >> 8) & 7;
    const int t = idx >> 11;                          // 0..47
    const int n = t * 16 + (l & 15);
    const int k = c * 32 + (l >> 4) * 8 + 2 * j;
    wfrag[idx] = pk2(whh[(size_t)n * D + k], whh[(size_t)n * D + k + 1]);
}

// ---------------------------------------------------------------------------
// Kernel 5: GRU recurrence — r21 version VERBATIM (best: 1.099 ms/dispatch).
// r22's hybrid MFMA∥dot2 regressed (+12%): at 2 waves/SIMD the dot2 stream
// shares the wave's serial ISSUE slots with MFMA — no independent wave to
// absorb it. Reverted.
// ---------------------------------------------------------------------------
__global__ __launch_bounds__(512, 1) void gru_scan_mfma(
    const float* __restrict__ xp, const unsigned int* __restrict__ wfrag,
    const float* __restrict__ bhh, float* __restrict__ x)
{
    __shared__ __align__(16) unsigned int h16_lds[D / 2];  // packed fp16 pairs
    __shared__ float gate_lds[G3];                         // W^T.h results
    const int tid  = threadIdx.x;
    const int w    = tid >> 6;          // wave 0..7
    const int l    = tid & 63;          // lane
    const int d    = tid;               // gate thread's output dim (tid<256)
    const int batch = blockIdx.x;

    // --- resident weights: 48 B-fragments = 192 u32/thread, coalesced ------
    half8 bf[6][8];
    {
        #pragma unroll
        for (int i = 0; i < 6; ++i)
            #pragma unroll
            for (int c = 0; c < 8; ++c) {
                const uint4 v = *(const uint4*)(
                    wfrag + ((size_t)(((w * 6 + i) * 8 + c) * 64 + l)) * 4);
                bf[i][c] = __builtin_bit_cast(half8, v);
            }
    }
    float bh_r = 0.f, bh_z = 0.f, bh_n = 0.f;
    if (tid < D) {
        bh_r = bhh[d];
        bh_z = bhh[D + d];
        bh_n = bhh[2 * D + d];
    }

    const float* xpb = xp + (size_t)batch * SEQ * G3;
    float* xb = x + (size_t)batch * SEQ * D;

    float hreg = 0.f;                   // fp32 h state, register-resident
    if (tid < D / 2) h16_lds[tid] = 0u;
    __syncthreads();

    const int lg = l >> 4;              // lane group 0..3
    for (int t = 0; t < SEQ; ++t) {
        // xp + residual loads early (tid<256); latency hides under MFMA
        float xr = 0.f, xz = 0.f, xn_ = 0.f, xold = 0.f;
        if (tid < D) {
            const float* xpt = xpb + (size_t)t * G3;
            xr   = xpt[d];
            xz   = xpt[D + d];
            xn_  = xpt[2 * D + d];
            xold = xb[(size_t)t * D + d];
        }

        // --- A fragments: h replicated across rows; broadcast LDS reads ----
        half8 af[8];
        #pragma unroll
        for (int c = 0; c < 8; ++c)
            af[c] = __builtin_bit_cast(half8,
                *(const uint4*)(h16_lds + 16 * c + 4 * lg));

        // --- MFMA phase: 6 tiles x 8 K-chunks, C accumulates K in-pipe -----
        #pragma unroll
        for (int i = 0; i < 6; ++i) {
            f32x4 cf = {0.f, 0.f, 0.f, 0.f};
            #pragma unroll
            for (int c = 0; c < 8; ++c)
                cf = __builtin_amdgcn_mfma_f32_16x16x32_f16(af[c], bf[i][c], cf, 0, 0, 0);
            if (l < 16) gate_lds[(w * 6 + i) * 16 + l] = cf[0];  // row 0
        }
        bar_lds();

        // --- gates (tid<256): native exp2/rcp, h in register ---------------
        if (tid < D) {
            float ar = gate_lds[d];
            float az = gate_lds[D + d];
            float an = gate_lds[2 * D + d];
            float r = fast_sigmoid(xr + ar + bh_r);
            float z = fast_sigmoid(xz + az + bh_z);
            float n = fast_tanh(xn_ + r * (an + bh_n));
            float hnew = (1.f - z) * n + z * hreg;
            hreg = hnew;
            // pack (h[d], h[d+1]) -> fp16 pair; neighbors are adjacent lanes
            float hn1 = __shfl_down(hnew, 1);
            if (!(d & 1)) {
                h16_lds[d >> 1] = pk2(hnew, hn1);
            }
            xb[(size_t)t * D + d] = xold + hnew;
        }
        bar_lds();
    }
}

// ---------------------------------------------------------------------------
// Kernel 6: final LN + mean-pool over sequence
// ---------------------------------------------------------------------------
__global__ __launch_bounds__(256) void pool_ln(
    const float* __restrict__ x, const float* __restrict__ st,
    const float* __restrict__ fsc, const float* __restrict__ fbi,
    float* __restrict__ emb)
{
    const int b = blockIdx.x;
    const int d = threadIdx.x;
    float acc = 0.f;
    for (int s = 0; s < SEQ; ++s) {
        int m = b * SEQ + s;
        acc += (x[(size_t)m * D + d] - st[2 * m]) * st[2 * m + 1];
    }
    emb[b * D + d] = (acc * (1.f / (float)SEQ)) * fsc[d] + fbi[d];
}

// ---------------------------------------------------------------------------
// Kernel 7: classification head (tiny). Single block.
// ---------------------------------------------------------------------------
__global__ __launch_bounds__(256) void head_mlp(
    const float* __restrict__ emb, const float* __restrict__ w1,
    const float* __restrict__ b1, const float* __restrict__ w2,
    const float* __restrict__ b2, float* __restrict__ out)
{
    __shared__ float es[NB][D + 1];
    __shared__ float h1[NB][128 + 1];
    const int t = threadIdx.x;
    for (int i = t; i < NB * D; i += 256) es[i / D][i % D] = emb[i];
    __syncthreads();
    for (int i = t; i < NB * 128; i += 256) {
        int bb = i / 128, j = i % 128;
        float a = b1[j];
        for (int k = 0; k < D; ++k) a = fmaf(es[bb][k], w1[(size_t)k * 128 + j], a);
        h1[bb][j] = gelu_exact(a);
    }
    __syncthreads();
    for (int i = t; i < NB * 8; i += 256) {
        int bb = i / 8, c = i % 8;
        float a = b2[c];
        for (int k = 0; k < 128; ++k) a = fmaf(h1[bb][k], w2[(size_t)k * 8 + c], a);
        out[i] = a;
    }
}

// ---------------------------------------------------------------------------
extern "C" void kernel_launch(void* const* d_in, const int* in_sizes, int n_in,
                              void* d_out, int out_size, void* d_ws, size_t ws_size,
                              hipStream_t stream)
{
    const float* wav  = (const float*)d_in[0];
    const float* cw   = (const float*)d_in[1];
    const float* pos  = (const float*)d_in[2];
    const float* lnsc = (const float*)d_in[3];
    const float* lnbi = (const float*)d_in[4];
    const float* wih  = (const float*)d_in[5];
    const float* whh  = (const float*)d_in[6];
    const float* bih  = (const float*)d_in[7];
    const float* bhh  = (const float*)d_in[8];
    const float* fsc  = (const float*)d_in[9];
    const float* fbi  = (const float*)d_in[10];
    const float* hw1  = (const float*)d_in[11];
    const float* hb1  = (const float*)d_in[12];
    const float* hw2  = (const float*)d_in[13];
    const float* hb2  = (const float*)d_in[14];

    float* ws    = (float*)d_ws;
    float* x     = ws;                        // 8,192,000 f
    float* xp    = x + (size_t)M_TOTAL * D;   // 24,576,000 f
    float* st    = xp + (size_t)M_TOTAL * G3; // 64,000 f
    unsigned int* wfrag = (unsigned int*)(st + 2 * M_TOTAL); // 98,304 u32
    float* emb   = (float*)(wfrag + 98304);   // 8,192 f

    conv_gelu_pos<<<dim3(M_TOTAL / 64, D / 64), 256, 0, stream>>>(wav, cw, pos, x);

    for (int l = 0; l < NL; ++l) {
        row_stats<<<M_TOTAL, 64, 0, stream>>>(x, st);
        ln_xp_mfma<<<dim3(M_TOTAL / 64, G3 / 64), 256, 0, stream>>>(
            x, st, lnsc + (size_t)l * D, lnbi + (size_t)l * D,
            wih + (size_t)l * G3 * D, bih + (size_t)l * G3, xp);
        pack_whh<<<384, 256, 0, stream>>>(whh + (size_t)l * G3 * D, wfrag);
        gru_scan_mfma<<<NB, 512, 0, stream>>>(
            xp, wfrag, bhh + (size_t)l * G3, x);
    }

    row_stats<<<M_TOTAL, 64, 0, stream>>>(x, st);
    pool_ln<<<NB, D, 0, stream>>>(x, st, fsc, fbi, emb);
    head_mlp<<<1, 256, 0, stream>>>(emb, hw1, hb1, hw2, hb2, (float*)d_out);
}